// Round 11
// baseline (492.307 us; speedup 1.0000x reference)
//
#include <hip/hip_runtime.h>
#include <stdint.h>

typedef unsigned short u16;
typedef __bf16 bf16x8 __attribute__((ext_vector_type(8)));
typedef float    f32x4 __attribute__((ext_vector_type(4)));
typedef unsigned short u16x8 __attribute__((ext_vector_type(8)));
typedef unsigned short u16x4 __attribute__((ext_vector_type(4)));

#define BB 8
#define SS 1024
#define EE 2048
#define HH 16
#define DD 128

__device__ __forceinline__ u16 f2bf(float f){
  union { float f; unsigned u; } v; v.f = f;
  unsigned r = v.u + 0x7FFFu + ((v.u >> 16) & 1u);
  return (u16)(r >> 16);
}
__device__ __forceinline__ float bf2f(u16 h){
  union { unsigned u; float f; } v; v.u = ((unsigned)h) << 16;
  return v.f;
}
__device__ __forceinline__ bf16x8 ld8(const u16* p){
  return __builtin_bit_cast(bf16x8, *(const u16x8*)p);
}

typedef __attribute__((address_space(1))) const unsigned int gas_u32;
typedef __attribute__((address_space(3))) unsigned int las_u32;
__device__ __forceinline__ void g2l16(const u16* g, u16* l){
  __builtin_amdgcn_global_load_lds((gas_u32*)g, (las_u32*)l, 16, 0, 0);
}

#define BARRIER() asm volatile("s_barrier" ::: "memory")
#define VMC(n)    asm volatile("s_waitcnt vmcnt(" #n ")" ::: "memory")

// ---------------- fused prep: cvt + 4 weight transposes + rope tables ----------------
__device__ __forceinline__ void trB(const float* __restrict__ W, u16* __restrict__ Wt,
                                    int K, int N, int bx, int by,
                                    float (*t)[33], int tid){
  int c = tid & 31, r = tid >> 5;
  #pragma unroll
  for (int i = 0; i < 32; i += 8)
    t[r+i][c] = W[(size_t)(by*32 + r + i)*N + bx*32 + c];
  __syncthreads();
  #pragma unroll
  for (int i = 0; i < 32; i += 8)
    Wt[(size_t)(bx*32 + r + i)*K + by*32 + c] = f2bf(t[c][r+i]);
}

__global__ __launch_bounds__(256) void prep(const float* __restrict__ x, u16* __restrict__ xb,
    const float* __restrict__ Wq,   u16* __restrict__ WqT,
    const float* __restrict__ Wkvd, u16* __restrict__ WkvdT,
    const float* __restrict__ Wku,  u16* __restrict__ WkuT,
    const float* __restrict__ Wvu,  u16* __restrict__ WvuT,
    float* __restrict__ cosb, float* __restrict__ sinb){
  __shared__ float t[32][33];
  const int bid = blockIdx.x, tid = threadIdx.x;
  if (bid < 8192){
    int i = (bid*256 + tid)*8;
    float4 v0 = *(const float4*)(x + i);
    float4 v1 = *(const float4*)(x + i + 4);
    u16x8 o;
    o[0]=f2bf(v0.x); o[1]=f2bf(v0.y); o[2]=f2bf(v0.z); o[3]=f2bf(v0.w);
    o[4]=f2bf(v1.x); o[5]=f2bf(v1.y); o[6]=f2bf(v1.z); o[7]=f2bf(v1.w);
    *(u16x8*)(xb + i) = o;
  } else if (bid < 12288){
    int k = bid - 8192;  trB(Wq,   WqT,   EE,  EE,  k & 63, k >> 6, t, tid);
  } else if (bid < 13312){
    int k = bid - 12288; trB(Wkvd, WkvdT, EE,  512, k & 15, k >> 4, t, tid);
  } else if (bid < 14336){
    int k = bid - 13312; trB(Wku,  WkuT,  512, EE,  k & 63, k >> 6, t, tid);
  } else if (bid < 15360){
    int k = bid - 14336; trB(Wvu,  WvuT,  512, EE,  k & 63, k >> 6, t, tid);
  } else {
    int i = (bid - 15360)*256 + tid;
    if (i < SS*48){
      int s = i / 48, j = i % 48;
      float freq = powf(10000.0f, -((float)(2*j)) / 96.0f);
      float e = (float)s * freq;
      cosb[i] = cosf(e);
      sinb[i] = sinf(e);
    }
  }
}

// ---------------- RoPE apply in-place on q and k, one launch ----------------
__global__ __launch_bounds__(256) void rope_apply2(u16* __restrict__ qp,
                                                   u16* __restrict__ kp,
                                                   const float* __restrict__ cosb,
                                                   const float* __restrict__ sinb){
  u16* base = blockIdx.y ? kp : qp;
  int t = blockIdx.x*256 + threadIdx.x;
  int row = t >> 4, h = t & 15, s = row & (SS-1);
  u16* p = base + (size_t)row*EE + h*DD + 32;
  float e[48], o[48];
  #pragma unroll
  for (int c = 0; c < 12; c++){
    u16x8 v = *(const u16x8*)(p + c*8);
    #pragma unroll
    for (int j = 0; j < 4; j++){
      e[c*4 + j] = bf2f(v[2*j]);
      o[c*4 + j] = bf2f(v[2*j+1]);
    }
  }
  u16 ob[96];
  #pragma unroll
  for (int j = 0; j < 48; j++){
    float cs = cosb[s*48 + j], sn = sinb[s*48 + j];
    ob[j]      = f2bf(e[j]*cs - o[j]*sn);
    ob[48 + j] = f2bf(o[j]*cs + e[j]*sn);
  }
  #pragma unroll
  for (int c = 0; c < 12; c++)
    *(u16x8*)(p + c*8) = *(const u16x8*)(ob + c*8);
}

// ---------------- GEMM 128^2 (m97 structure) for N=512, XCD-chunked ----------------
__global__ __launch_bounds__(256) void gemm_bt(const u16* __restrict__ A,
    const u16* __restrict__ Bt, u16* __restrict__ C, int M, int N, int K){
  __shared__ u16 Al[128*32];
  __shared__ u16 Bl[128*32];
  const int tid = threadIdx.x;
  const int lane = tid & 63, w = tid >> 6;
  const int wr = w >> 1, wc = w & 1;
  const int l15 = lane & 15, l4 = lane >> 4;
  const int id = blockIdx.y * 4 + blockIdx.x;
  const int xcd = id & 7, j = id >> 3;
  const int bm = (xcd*8 + (j >> 2)) * 128;
  const int bn = (j & 3) * 128;
  const int srow = tid >> 2;
  const int skc  = (tid & 3) * 8;
  const u16* ga = A  + (size_t)(bm + srow)*K + skc;
  const u16* gb = Bt + (size_t)(bn + srow)*K + skc;
  u16* la = Al + w*512;
  u16* lb = Bl + w*512;
  f32x4 acc[4][4] = {};
  for (int k0 = 0; k0 < K; k0 += 32){
    __syncthreads();
    g2l16(ga + k0,          la);
    g2l16(ga + 64*K + k0,   la + 2048);
    g2l16(gb + k0,          lb);
    g2l16(gb + 64*K + k0,   lb + 2048);
    __syncthreads();
    bf16x8 af[4], bfr[4];
    #pragma unroll
    for (int m = 0; m < 4; m++) af[m]  = ld8(Al + (wr*64 + m*16 + l15)*32 + l4*8);
    #pragma unroll
    for (int n = 0; n < 4; n++) bfr[n] = ld8(Bl + (wc*64 + n*16 + l15)*32 + l4*8);
    #pragma unroll
    for (int m = 0; m < 4; m++)
      #pragma unroll
      for (int n = 0; n < 4; n++)
        acc[m][n] = __builtin_amdgcn_mfma_f32_16x16x32_bf16(af[m], bfr[n], acc[m][n], 0, 0, 0);
  }
  #pragma unroll
  for (int m = 0; m < 4; m++)
    #pragma unroll
    for (int n = 0; n < 4; n++)
      #pragma unroll
      for (int r = 0; r < 4; r++){
        int row = bm + wr*64 + m*16 + l4*4 + r;
        int col = bn + wc*64 + n*16 + l15;
        C[(size_t)row*N + col] = f2bf(acc[m][n][r]);
      }
}

// ---------------- GEMM 256x128, A-in-LDS (dbuf) + B-direct-from-L2 (reg dbuf) ----------------
// 8 waves = 4M x 2N, wave tile 64x64, acc[4][4]. 2 blocks/CU (64KB LDS, <=128 VGPR).
// One barrier per K-tile; stages+B-loads issued at tile start, VMC(0) at tile end.
#define AFR(ab, mf, ks) ld8(&AL[ab][wr>>1][(((wr&1)*64 + (mf)*16 + l15))*64 + ((((ks)*4 + l4) ^ r7) << 3)])

#define STAGE_A(ab, h, kt) stage2(aRow, (h), (kt), K, &AL[ab][h][0], wj0)
#define STAGE_A2(ab, kt)   do{ STAGE_A(ab, 0, kt); STAGE_A(ab, 1, kt); }while(0)

__device__ __forceinline__ void stage2(const u16* rowbase, int h, int kt, int K,
                                       u16* lds, int wj0){
  const u16* g = rowbase + (size_t)h*128*K + kt*64;
  g2l16(g,               lds + wj0*512);
  g2l16(g + (size_t)8*K, lds + wj0*512 + 512);
}

#define LOADB(dst, kt) do{                                                         \
  _Pragma("unroll")                                                                \
  for (int nf = 0; nf < 4; nf++){                                                  \
    dst[nf][0] = ld8(bW + (size_t)(nf*16)*K + (kt)*64);                            \
    dst[nf][1] = ld8(bW + (size_t)(nf*16)*K + (kt)*64 + 32);                       \
  }                                                                                \
}while(0)

#define TILE(ab, BQ, BQN, ktn) do{                                                 \
  STAGE_A2((ab)^1, ktn);                                                           \
  LOADB(BQN, ktn);                                                                 \
  __builtin_amdgcn_sched_barrier(0);                                               \
  __builtin_amdgcn_s_setprio(1);                                                   \
  _Pragma("unroll")                                                                \
  for (int ks = 0; ks < 2; ks++)                                                   \
    _Pragma("unroll")                                                              \
    for (int mf = 0; mf < 4; mf++){                                                \
      bf16x8 af = AFR(ab, mf, ks);                                                 \
      _Pragma("unroll")                                                            \
      for (int nf = 0; nf < 4; nf++)                                               \
        acc[mf][nf] = __builtin_amdgcn_mfma_f32_16x16x32_bf16(af, BQ[nf][ks], acc[mf][nf], 0, 0, 0); \
    }                                                                              \
  __builtin_amdgcn_s_setprio(0);                                                   \
  VMC(0);                                                                          \
  BARRIER();                                                                       \
}while(0)

__global__ __launch_bounds__(512, 4) void gemm8(const u16* __restrict__ A,
    const u16* __restrict__ Bt, u16* __restrict__ C0, u16* __restrict__ C1,
    int K, int Nout0, int Nout1, int nsplit, int vt){
  __shared__ u16 AL[2][2][128*64];   // 64 KB: A tile 256x64, double-buffered
  const int tid = threadIdx.x, lane = tid & 63, w = tid >> 6;
  const int wr = w >> 1, wc = w & 1;           // 4M x 2N wave grid
  const int l15 = lane & 15, l4 = lane >> 4;
  const int r7 = l15 & 7;
  // XCD chunk swizzle: bn-chunked so each XCD's B slice is L2-resident
  const int nbx = gridDim.x;                   // N/128 (pow2)
  const int bnp = nbx >> 3;                    // bn chunks per XCD (pow2)
  const int lbn = __popc(bnp - 1);
  const int id  = blockIdx.y * nbx + blockIdx.x;
  const int xcd = id & 7, j = id >> 3;
  const int bn  = (xcd*bnp + (j & (bnp - 1))) * 128;
  const int bm  = (j >> lbn) * 256;
  const int wj0 = w*2;
  const int cswz = (lane & 7) ^ (lane >> 3);
  const u16* aRow = A  + (size_t)(bm + wj0*8 + (lane>>3))*K + cswz*8;
  const u16* bW   = Bt + (size_t)(bn + wc*64 + l15)*K + l4*8;

  const int nkt = K >> 6;
  const int niter = nkt >> 1;

  f32x4 acc[4][4] = {};
  bf16x8 bqA[4][2], bqB[4][2];

  // prologue: A(0)->AL[0], B(0)->bqA
  STAGE_A2(0, 0);
  LOADB(bqA, 0);
  VMC(0);
  BARRIER();

  for (int it = 0; it < niter; ++it){
    const int kt1 = 2*it + 1;
    int kt2 = 2*it + 2; if (kt2 >= nkt) kt2 -= nkt;   // wrap: harmless re-read
    TILE(0, bqA, bqB, kt1);    // compute tile 2it;   stage A(kt1)->AL[1], B(kt1)->bqB
    TILE(1, bqB, bqA, kt2);    // compute tile 2it+1; stage A(kt2)->AL[0], B(kt2)->bqA
  }
  asm volatile("s_waitcnt vmcnt(0)" ::: "memory");

  if (vt && bn >= nsplit){
    // transposed store: C1 is vpT[(b*16 + head)*128 + d][1024 s]
    const int bcol = bn - nsplit;
    #pragma unroll
    for (int mf = 0; mf < 4; mf++)
      #pragma unroll
      for (int nf = 0; nf < 4; nf++){
        int row0 = bm + wr*64 + mf*16 + l4*4;
        int col  = bcol + wc*64 + nf*16 + l15;
        int bh = (row0 >> 10)*16 + (col >> 7);
        int d  = col & 127;
        int s  = row0 & 1023;
        u16x4 pk;
        #pragma unroll
        for (int r = 0; r < 4; r++) pk[r] = f2bf(acc[mf][nf][r]);
        *(u16x4*)(C1 + (((size_t)(bh*128 + d)) << 10) + s) = pk;
      }
  } else {
    u16* Cd = (bn < nsplit) ? C0 : C1;
    const int No = (bn < nsplit) ? Nout0 : Nout1;
    const int bcol = (bn < nsplit) ? bn : bn - nsplit;
    #pragma unroll
    for (int mf = 0; mf < 4; mf++)
      #pragma unroll
      for (int nf = 0; nf < 4; nf++)
        #pragma unroll
        for (int r = 0; r < 4; r++){
          int row = bm + wr*64 + mf*16 + l4*4 + r;
          int col = bcol + wc*64 + nf*16 + l15;
          Cd[(size_t)row*No + col] = f2bf(acc[mf][nf][r]);
        }
  }
}

// ---------------- Flash attention v6: swapped-operand in-register softmax ----------------
#define PLW 40   // P row stride in u16 (80 B): bank stride 20 -> 2-way max, 16B-aligned

__global__ __launch_bounds__(512) void attn(const u16* __restrict__ qp,
                                            const u16* __restrict__ kp,
                                            const u16* __restrict__ vpT,
                                            float* __restrict__ out){
  __shared__ u16 Kl[2][64*128];   // 32768 B
  __shared__ u16 Vl[2][128*64];   // 32768 B
  __shared__ u16 Pl[8][16*PLW];   // 10240 B  -> total 75776 B (2 blocks/CU)
  const int tid = threadIdx.x, lane = tid & 63, w = tid >> 6;
  const int l15 = lane & 15, l4 = lane >> 4;
  const int qt = 7 - blockIdx.y;              // heavy tiles dispatch first
  const int bh = blockIdx.x;
  const int b = bh >> 4, h = bh & 15;
  const int qbase = qt*128;
  const int qmin = qbase + w*16;
  const int qg = qmin + l15;                  // this lane's q row
  const float c = 0.12751920700948998f;       // (1/sqrt(128)) * log2(e)
  const float THR = 62.7f;                    // defer-max threshold (2^8 bound)

  const size_t rowq = (size_t)(b*SS + qg)*EE + h*DD;
  bf16x8 qf[4];
  #pragma unroll
  for (int kk = 0; kk < 4; kk++) qf[kk] = ld8(qp + rowq + kk*32 + l4*8);
  #pragma unroll
  for (int kk = 0; kk < 4; kk++) asm volatile("" : "+v"(qf[kk]));

  f32x4 ao[8] = {};                           // O^T: [d = n8*16 + l4*4 + r][q = l15]
  float mi = -3e38f, li = 0.0f;

  const int ntiles = 2*qt + 2;
  const int vcc = lane & 7;

  #pragma unroll
  for (int q = 0; q < 2; q++){
    int r = w*8 + q*4 + (lane>>4);
    g2l16(kp + (size_t)(b*SS + r)*EE + h*DD + (((lane&15) ^ (r&7))<<3),
          &Kl[0][0] + w*1024 + q*512);
    int d = w*16 + q*8 + (lane>>3);
    g2l16(vpT + (size_t)(bh*DD + d)*SS + ((vcc ^ (d&7))<<3),
          &Vl[0][0] + w*1024 + q*512);
  }

  for (int t = 0; t < ntiles; t++){
    const int kv0 = t*64;
    const int buf = t & 1;
    {
      const int kvn = (t + 1 < ntiles) ? kv0 + 64 : kv0;
      #pragma unroll
      for (int q = 0; q < 2; q++){
        int r = w*8 + q*4 + (lane>>4);
        g2l16(kp + (size_t)(b*SS + kvn + r)*EE + h*DD + (((lane&15) ^ (r&7))<<3),
              &Kl[buf^1][0] + w*1024 + q*512);
        int d = w*16 + q*8 + (lane>>3);
        g2l16(vpT + (size_t)(bh*DD + d)*SS + kvn + ((vcc ^ (d&7))<<3),
              &Vl[buf^1][0] + w*1024 + q*512);
      }
    }
    VMC(4);
    BARRIER();

    if (kv0 <= qmin + 15){
      float sv[4][4];
      __builtin_amdgcn_s_setprio(1);
      #pragma unroll
      for (int nt = 0; nt < 4; nt++){
        f32x4 sacc = {};
        #pragma unroll
        for (int kk = 0; kk < 4; kk++){
          bf16x8 kf = ld8(&Kl[buf][0] + (nt*16 + l15)*128 + (((kk*4 + l4) ^ (l15&7))<<3));
          sacc = __builtin_amdgcn_mfma_f32_16x16x32_bf16(kf, qf[kk], sacc, 0, 0, 0);
        }
        #pragma unroll
        for (int r = 0; r < 4; r++) sv[nt][r] = sacc[r];
      }
      __builtin_amdgcn_s_setprio(0);
      if (kv0 + 63 > qmin){
        #pragma unroll
        for (int nt = 0; nt < 4; nt++)
          #pragma unroll
          for (int r = 0; r < 4; r++){
            int kg = kv0 + nt*16 + l4*4 + r;
            if (kg > qg) sv[nt][r] = -3e38f;
          }
      }
      float mx = sv[0][0];
      #pragma unroll
      for (int nt = 0; nt < 4; nt++)
        #pragma unroll
        for (int r = 0; r < 4; r++) mx = fmaxf(mx, sv[nt][r]);
      mx = fmaxf(mx, __shfl_xor(mx, 16));
      mx = fmaxf(mx, __shfl_xor(mx, 32));
      if (__any(mx > mi + THR)){
        float mnew = fmaxf(mi, mx);
        float alpha = __builtin_amdgcn_exp2f((mi - mnew)*c);
        li *= alpha;
        #pragma unroll
        for (int n8 = 0; n8 < 8; n8++) ao[n8] *= alpha;
        mi = mnew;
      }
      const float mnc = mi*c;
      float pout[4][4];
      float rs = 0.0f;
      #pragma unroll
      for (int nt = 0; nt < 4; nt++)
        #pragma unroll
        for (int r = 0; r < 4; r++){
          float pv = __builtin_amdgcn_exp2f(__builtin_fmaf(sv[nt][r], c, -mnc));
          pout[nt][r] = pv; rs += pv;
        }
      rs += __shfl_xor(rs, 16);
      rs += __shfl_xor(rs, 32);
      li += rs;
      #pragma unroll
      for (int kk = 0; kk < 2; kk++){
        #pragma unroll
        for (int ntl = 0; ntl < 2; ntl++){
          int nt = kk*2 + ntl;
          u16x4 pk;
          #pragma unroll
          for (int r = 0; r < 4; r++) pk[r] = f2bf(pout[nt][r]);
          *(u16x4*)(&Pl[w][l15*PLW + ntl*16 + l4*4]) = pk;
        }
        bf16x8 pa = ld8(&Pl[w][l15*PLW + l4*8]);
        __builtin_amdgcn_s_setprio(1);
        #pragma unroll
        for (int n8 = 0; n8 < 8; n8++){
          bf16x8 vf = ld8(&Vl[buf][0] + (n8*16 + l15)*64 + (((kk*4 + l4) ^ (l15&7))<<3));
          ao[n8] = __builtin_amdgcn_mfma_f32_16x16x32_bf16(vf, pa, ao[n8], 0, 0, 0);
        }
        __builtin_amdgcn_s_setprio(0);
      }
    }
    BARRIER();
  }
  asm volatile("s_waitcnt vmcnt(0)" ::: "memory");

  const float inv = 1.0f / li;
  const size_t orow = (size_t)(b*SS + qg)*EE + h*DD;
  #pragma unroll
  for (int n8 = 0; n8 < 8; n8++){
    f32x4 o = ao[n8]*inv;
    *(float4*)(out + orow + n8*16 + l4*4) = __builtin_bit_cast(float4, o);
  }
}

// ---------------- launch ----------------
extern "C" void kernel_launch(void* const* d_in, const int* in_sizes, int n_in,
                              void* d_out, int out_size, void* d_ws, size_t ws_size,
                              hipStream_t stream){
  const float* x    = (const float*)d_in[0];
  const float* Wq   = (const float*)d_in[1];
  const float* Wkvd = (const float*)d_in[2];
  const float* Wku  = (const float*)d_in[3];
  const float* Wvu  = (const float*)d_in[4];
  float* out = (float*)d_out;
  char* ws = (char*)d_ws;

  u16*   xb    = (u16*)  (ws);                 // 33,554,432 B
  u16*   WqT   = (u16*)  (ws +  33554432);     //  8,388,608
  u16*   WkvdT = (u16*)  (ws +  41943040);     //  2,097,152
  u16*   WkuT  = (u16*)  (ws +  44040192);     //  2,097,152  (WvuT adjacent -> 4096xK panel)
  u16*   WvuT  = (u16*)  (ws +  46137344);     //  2,097,152
  float* cosb  = (float*)(ws +  48234496);     //    196,608
  float* sinb  = (float*)(ws +  48431104);     //    196,608
  u16*   qp    = (u16*)  (ws +  48627712);     // 33,554,432
  u16*   ckv   = (u16*)  (ws +  82182144);     //  8,388,608
  u16*   kp    = (u16*)  (ws +  90570752);     // 33,554,432
  u16*   vpT   = (u16*)  (ws + 124125184);     // 33,554,432 (transposed: [bh*128+d][1024])

  prep<<<15552, 256, 0, stream>>>(x, xb, Wq, WqT, Wkvd, WkvdT,
                                  Wku, WkuT, Wvu, WvuT, cosb, sinb);

  // q = x @ Wq  (M=8192, N=2048, K=2048): grid 16x32 = 512 blocks, 2 blocks/CU
  gemm8<<<dim3(EE/128, (BB*SS)/256), 512, 0, stream>>>(xb, WqT, qp, qp,
                                                       EE, EE, EE, EE, 0);
  // c_kv = x @ Wkv_down (N=512), 128^2 kernel, 256 blocks, XCD-chunked
  gemm_bt<<<dim3(512/128, (BB*SS)/128), 256, 0, stream>>>(xb, WkvdT, ckv, BB*SS, 512, EE);
  // fused k/v up-projection (N=4096, K=512): grid 32x32 = 1024 blocks; V transposed
  gemm8<<<dim3(4096/128, (BB*SS)/256), 512, 0, stream>>>(ckv, WkuT, kp, vpT,
                                                         512, EE, 0, EE, 1);

  rope_apply2<<<dim3((BB*SS*HH)/256, 2), 256, 0, stream>>>(qp, kp, cosb, sinb);

  attn<<<dim3(BB*HH, SS/128), 512, 0, stream>>>(qp, kp, vpT, out);
}

// Round 12
// 296.574 us; speedup vs baseline: 1.6600x; 1.6600x over previous
//
#include <hip/hip_runtime.h>
#include <stdint.h>

typedef unsigned short u16;
typedef __bf16 bf16x8 __attribute__((ext_vector_type(8)));
typedef float    f32x4 __attribute__((ext_vector_type(4)));
typedef unsigned short u16x8 __attribute__((ext_vector_type(8)));
typedef unsigned short u16x4 __attribute__((ext_vector_type(4)));

#define BB 8
#define SS 1024
#define EE 2048
#define HH 16
#define DD 128

__device__ __forceinline__ u16 f2bf(float f){
  union { float f; unsigned u; } v; v.f = f;
  unsigned r = v.u + 0x7FFFu + ((v.u >> 16) & 1u);
  return (u16)(r >> 16);
}
__device__ __forceinline__ float bf2f(u16 h){
  union { unsigned u; float f; } v; v.u = ((unsigned)h) << 16;
  return v.f;
}
__device__ __forceinline__ bf16x8 ld8(const u16* p){
  return __builtin_bit_cast(bf16x8, *(const u16x8*)p);
}

typedef __attribute__((address_space(1))) const unsigned int gas_u32;
typedef __attribute__((address_space(3))) unsigned int las_u32;
__device__ __forceinline__ void g2l16(const u16* g, u16* l){
  __builtin_amdgcn_global_load_lds((gas_u32*)g, (las_u32*)l, 16, 0, 0);
}

#define BARRIER() asm volatile("s_barrier" ::: "memory")
#define VMC(n)    asm volatile("s_waitcnt vmcnt(" #n ")" ::: "memory")

// ---------------- fused prep: cvt + 4 weight transposes + rope tables ----------------
__device__ __forceinline__ void trB(const float* __restrict__ W, u16* __restrict__ Wt,
                                    int K, int N, int bx, int by,
                                    float (*t)[33], int tid){
  int c = tid & 31, r = tid >> 5;
  #pragma unroll
  for (int i = 0; i < 32; i += 8)
    t[r+i][c] = W[(size_t)(by*32 + r + i)*N + bx*32 + c];
  __syncthreads();
  #pragma unroll
  for (int i = 0; i < 32; i += 8)
    Wt[(size_t)(bx*32 + r + i)*K + by*32 + c] = f2bf(t[c][r+i]);
}

__global__ __launch_bounds__(256) void prep(const float* __restrict__ x, u16* __restrict__ xb,
    const float* __restrict__ Wq,   u16* __restrict__ WqT,
    const float* __restrict__ Wkvd, u16* __restrict__ WkvdT,
    const float* __restrict__ Wku,  u16* __restrict__ WkuT,
    const float* __restrict__ Wvu,  u16* __restrict__ WvuT,
    float* __restrict__ cosb, float* __restrict__ sinb){
  __shared__ float t[32][33];
  const int bid = blockIdx.x, tid = threadIdx.x;
  if (bid < 8192){
    int i = (bid*256 + tid)*8;
    float4 v0 = *(const float4*)(x + i);
    float4 v1 = *(const float4*)(x + i + 4);
    u16x8 o;
    o[0]=f2bf(v0.x); o[1]=f2bf(v0.y); o[2]=f2bf(v0.z); o[3]=f2bf(v0.w);
    o[4]=f2bf(v1.x); o[5]=f2bf(v1.y); o[6]=f2bf(v1.z); o[7]=f2bf(v1.w);
    *(u16x8*)(xb + i) = o;
  } else if (bid < 12288){
    int k = bid - 8192;  trB(Wq,   WqT,   EE,  EE,  k & 63, k >> 6, t, tid);
  } else if (bid < 13312){
    int k = bid - 12288; trB(Wkvd, WkvdT, EE,  512, k & 15, k >> 4, t, tid);
  } else if (bid < 14336){
    int k = bid - 13312; trB(Wku,  WkuT,  512, EE,  k & 63, k >> 6, t, tid);
  } else if (bid < 15360){
    int k = bid - 14336; trB(Wvu,  WvuT,  512, EE,  k & 63, k >> 6, t, tid);
  } else {
    int i = (bid - 15360)*256 + tid;
    if (i < SS*48){
      int s = i / 48, j = i % 48;
      float freq = powf(10000.0f, -((float)(2*j)) / 96.0f);
      float e = (float)s * freq;
      cosb[i] = cosf(e);
      sinb[i] = sinf(e);
    }
  }
}

// ---------------- RoPE apply in-place on q and k, one launch ----------------
__global__ __launch_bounds__(256) void rope_apply2(u16* __restrict__ qp,
                                                   u16* __restrict__ kp,
                                                   const float* __restrict__ cosb,
                                                   const float* __restrict__ sinb){
  u16* base = blockIdx.y ? kp : qp;
  int t = blockIdx.x*256 + threadIdx.x;
  int row = t >> 4, h = t & 15, s = row & (SS-1);
  u16* p = base + (size_t)row*EE + h*DD + 32;
  float e[48], o[48];
  #pragma unroll
  for (int c = 0; c < 12; c++){
    u16x8 v = *(const u16x8*)(p + c*8);
    #pragma unroll
    for (int j = 0; j < 4; j++){
      e[c*4 + j] = bf2f(v[2*j]);
      o[c*4 + j] = bf2f(v[2*j+1]);
    }
  }
  u16 ob[96];
  #pragma unroll
  for (int j = 0; j < 48; j++){
    float cs = cosb[s*48 + j], sn = sinb[s*48 + j];
    ob[j]      = f2bf(e[j]*cs - o[j]*sn);
    ob[48 + j] = f2bf(o[j]*cs + e[j]*sn);
  }
  #pragma unroll
  for (int c = 0; c < 12; c++)
    *(u16x8*)(p + c*8) = *(const u16x8*)(ob + c*8);
}

// ---------------- GEMM 128^2 (m97 structure), XCD bm-chunked, split/vt outputs ----------------
// grid (nbx pow2, nby mult of 8). cols < nsplit -> C0 (stride Nout0); else C1
// (normal with stride Nout0 if vt=0, transposed V layout if vt=1).
__global__ __launch_bounds__(256) void gemm_bt(const u16* __restrict__ A,
    const u16* __restrict__ Bt, u16* __restrict__ C0, u16* __restrict__ C1,
    int K, int Nout0, int nsplit, int vt){
  __shared__ u16 Al[128*32];
  __shared__ u16 Bl[128*32];
  const int tid = threadIdx.x;
  const int lane = tid & 63, w = tid >> 6;
  const int wr = w >> 1, wc = w & 1;
  const int l15 = lane & 15, l4 = lane >> 4;
  // XCD bm-chunk swizzle
  const int nbx = gridDim.x;
  const int lbn = __popc(nbx - 1);
  const int id  = blockIdx.y * nbx + blockIdx.x;
  const int xcd = id & 7, j = id >> 3;
  const int rpx = gridDim.y >> 3;
  const int bm  = (xcd*rpx + (j >> lbn)) * 128;
  const int bn  = (j & (nbx - 1)) * 128;
  const int srow = tid >> 2;
  const int skc  = (tid & 3) * 8;
  const u16* ga = A  + (size_t)(bm + srow)*K + skc;
  const u16* gb = Bt + (size_t)(bn + srow)*K + skc;
  u16* la = Al + w*512;
  u16* lb = Bl + w*512;
  f32x4 acc[4][4] = {};
  for (int k0 = 0; k0 < K; k0 += 32){
    __syncthreads();
    g2l16(ga + k0,          la);
    g2l16(ga + 64*K + k0,   la + 2048);
    g2l16(gb + k0,          lb);
    g2l16(gb + 64*K + k0,   lb + 2048);
    __syncthreads();
    bf16x8 af[4], bfr[4];
    #pragma unroll
    for (int m = 0; m < 4; m++) af[m]  = ld8(Al + (wr*64 + m*16 + l15)*32 + l4*8);
    #pragma unroll
    for (int n = 0; n < 4; n++) bfr[n] = ld8(Bl + (wc*64 + n*16 + l15)*32 + l4*8);
    #pragma unroll
    for (int m = 0; m < 4; m++)
      #pragma unroll
      for (int n = 0; n < 4; n++)
        acc[m][n] = __builtin_amdgcn_mfma_f32_16x16x32_bf16(af[m], bfr[n], acc[m][n], 0, 0, 0);
  }
  if (vt && bn >= nsplit){
    // transposed store: C1 is vpT[(b*16 + head)*128 + d][1024 s]
    const int bcol = bn - nsplit;
    #pragma unroll
    for (int m = 0; m < 4; m++)
      #pragma unroll
      for (int n = 0; n < 4; n++){
        int row0 = bm + wr*64 + m*16 + l4*4;
        int col  = bcol + wc*64 + n*16 + l15;
        int bh = (row0 >> 10)*16 + (col >> 7);
        int d  = col & 127;
        int s  = row0 & 1023;
        u16x4 pk;
        #pragma unroll
        for (int r = 0; r < 4; r++) pk[r] = f2bf(acc[m][n][r]);
        *(u16x4*)(C1 + (((size_t)(bh*128 + d)) << 10) + s) = pk;
      }
  } else {
    u16* Cd = (bn < nsplit) ? C0 : C1;
    const int bcol = (bn < nsplit) ? bn : bn - nsplit;
    #pragma unroll
    for (int m = 0; m < 4; m++)
      #pragma unroll
      for (int n = 0; n < 4; n++)
        #pragma unroll
        for (int r = 0; r < 4; r++){
          int row = bm + wr*64 + m*16 + l4*4 + r;
          int col = bcol + wc*64 + n*16 + l15;
          Cd[(size_t)row*Nout0 + col] = f2bf(acc[m][n][r]);
        }
  }
}

// ---------------- GEMM 256^2, 8-phase, static 2x2 buffers, XCD-chunked (R10) ----------------
#define AFR(ab, mf, ks) ld8(&AL[ab][wr][((mf)*16 + l15)*64 + ((((ks)*4 + l4) ^ r7) << 3)])
#define BFR(bb, nf, ks) ld8(&BL[bb][wc>>1][(((wc&1)*64 + (nf)*16 + l15))*64 + ((((ks)*4 + l4) ^ r7) << 3)])

#define STAGE_A(ab, h, kt) stage2(aRow, (h), (kt), K, &AL[ab][h][0], wj0)
#define STAGE_A2(ab, kt)   do{ STAGE_A(ab, 0, kt); STAGE_A(ab, 1, kt); }while(0)
#define STAGE_B(bb, h, kt) stage2(bRow, (h), (kt), K, &BL[bb][h][0], wj0)

__device__ __forceinline__ void stage2(const u16* rowbase, int h, int kt, int K,
                                       u16* lds, int wj0){
  const u16* g = rowbase + (size_t)h*128*K + kt*64;
  g2l16(g,               lds + wj0*512);
  g2l16(g + (size_t)8*K, lds + wj0*512 + 512);
}

#define PHASE(ab, q, LOADB, STAGE, DOVM) do{                                       \
  bf16x8 a00 = AFR(ab, 2*(q)  , 0);                                               \
  bf16x8 a01 = AFR(ab, 2*(q)  , 1);                                               \
  bf16x8 a10 = AFR(ab, 2*(q)+1, 0);                                               \
  bf16x8 a11 = AFR(ab, 2*(q)+1, 1);                                               \
  if (LOADB){                                                                      \
    _Pragma("unroll")                                                              \
    for (int nf = 0; nf < 4; nf++){ bq[nf][0]=BFR(ab,nf,0); bq[nf][1]=BFR(ab,nf,1); } \
  }                                                                                \
  STAGE;                                                                           \
  if (DOVM) VMC(4);                                                                \
  BARRIER();                                                                       \
  __builtin_amdgcn_s_setprio(1);                                                   \
  _Pragma("unroll")                                                                \
  for (int nf = 0; nf < 4; nf++){                                                  \
    acc[2*(q)][nf]   = __builtin_amdgcn_mfma_f32_16x16x32_bf16(a00, bq[nf][0], acc[2*(q)][nf],0,0,0);   \
    acc[2*(q)+1][nf] = __builtin_amdgcn_mfma_f32_16x16x32_bf16(a10, bq[nf][0], acc[2*(q)+1][nf],0,0,0); \
  }                                                                                \
  _Pragma("unroll")                                                                \
  for (int nf = 0; nf < 4; nf++){                                                  \
    acc[2*(q)][nf]   = __builtin_amdgcn_mfma_f32_16x16x32_bf16(a01, bq[nf][1], acc[2*(q)][nf],0,0,0);   \
    acc[2*(q)+1][nf] = __builtin_amdgcn_mfma_f32_16x16x32_bf16(a11, bq[nf][1], acc[2*(q)+1][nf],0,0,0); \
  }                                                                                \
  __builtin_amdgcn_s_setprio(0);                                                   \
  BARRIER();                                                                       \
  __builtin_amdgcn_sched_barrier(0);                                               \
}while(0)

__global__ __launch_bounds__(512, 2) void gemm8(const u16* __restrict__ A,
    const u16* __restrict__ Bt, u16* __restrict__ C0, u16* __restrict__ C1,
    int K, int Nout0, int Nout1, int nsplit, int vt){
  __shared__ u16 AL[2][2][128*64];   // 64 KB
  __shared__ u16 BL[2][2][128*64];   // 64 KB -> 128 KiB total
  const int tid = threadIdx.x, lane = tid & 63, w = tid >> 6;
  const int wr = w >> 2, wc = w & 3;
  const int l15 = lane & 15, l4 = lane >> 4;
  const int r7 = l15 & 7;
  const int nbx = gridDim.x;
  const int lb  = __popc(nbx - 1);
  const int id  = blockIdx.y * nbx + blockIdx.x;
  const int xcd = id & 7, j = id >> 3;
  const int rpx = gridDim.y >> 3;
  const int bm  = (xcd*rpx + (j >> lb)) * 256;
  const int bn  = (j & (nbx - 1)) * 256;
  const int wj0 = w*2;
  const int cswz = (lane & 7) ^ (lane >> 3);
  const u16* aRow = A  + (size_t)(bm + wj0*8 + (lane>>3))*K + cswz*8;
  const u16* bRow = Bt + (size_t)(bn + wj0*8 + (lane>>3))*K + cswz*8;

  const int nkt = K >> 6;
  const int niter = nkt >> 1;

  STAGE_A2(0, 0);
  STAGE_B(0, 0, 0); STAGE_B(0, 1, 0);
  STAGE_B(1, 0, 1); STAGE_B(1, 1, 1);
  VMC(4);
  BARRIER();

  f32x4 acc[8][4] = {};
  bf16x8 bq[4][2];

  for (int it = 0; it < niter; ++it){
    const int kt1 = 2*it + 1;
    int kt2 = 2*it + 2; if (kt2 >= nkt) kt2 -= nkt;
    int kt3 = 2*it + 3; if (kt3 >= nkt) kt3 -= nkt;
    PHASE(0, 0, 1, STAGE_A2(1, kt1),    0);
    PHASE(0, 1, 0, STAGE_B(0, 0, kt2),  0);
    PHASE(0, 2, 0, STAGE_B(0, 1, kt2),  0);
    PHASE(0, 3, 0, ;,                   1);
    PHASE(1, 0, 1, STAGE_A2(0, kt2),    0);
    PHASE(1, 1, 0, STAGE_B(1, 0, kt3),  0);
    PHASE(1, 2, 0, STAGE_B(1, 1, kt3),  0);
    PHASE(1, 3, 0, ;,                   1);
  }
  asm volatile("s_waitcnt vmcnt(0)" ::: "memory");

  if (vt && bn >= nsplit){
    const int bcol = bn - nsplit;
    #pragma unroll
    for (int mf = 0; mf < 8; mf++)
      #pragma unroll
      for (int nf = 0; nf < 4; nf++){
        int row0 = bm + wr*128 + mf*16 + l4*4;
        int col  = bcol + wc*64 + nf*16 + l15;
        int bh = (row0 >> 10)*16 + (col >> 7);
        int d  = col & 127;
        int s  = row0 & 1023;
        u16x4 pk;
        #pragma unroll
        for (int r = 0; r < 4; r++) pk[r] = f2bf(acc[mf][nf][r]);
        *(u16x4*)(C1 + (((size_t)(bh*128 + d)) << 10) + s) = pk;
      }
  } else {
    u16* Cd = (bn < nsplit) ? C0 : C1;
    const int No = (bn < nsplit) ? Nout0 : Nout1;
    const int bcol = (bn < nsplit) ? bn : bn - nsplit;
    #pragma unroll
    for (int mf = 0; mf < 8; mf++)
      #pragma unroll
      for (int nf = 0; nf < 4; nf++)
        #pragma unroll
        for (int r = 0; r < 4; r++){
          int row = bm + wr*128 + mf*16 + l4*4 + r;
          int col = bcol + wc*64 + nf*16 + l15;
          Cd[(size_t)row*No + col] = f2bf(acc[mf][nf][r]);
        }
  }
}

// ---------------- Flash attention v6: swapped-operand in-register softmax ----------------
#define PLW 40   // P row stride in u16 (80 B): bank stride 20 -> 2-way max, 16B-aligned

__global__ __launch_bounds__(512) void attn(const u16* __restrict__ qp,
                                            const u16* __restrict__ kp,
                                            const u16* __restrict__ vpT,
                                            float* __restrict__ out){
  __shared__ u16 Kl[2][64*128];   // 32768 B
  __shared__ u16 Vl[2][128*64];   // 32768 B
  __shared__ u16 Pl[8][16*PLW];   // 10240 B  -> total 75776 B (2 blocks/CU)
  const int tid = threadIdx.x, lane = tid & 63, w = tid >> 6;
  const int l15 = lane & 15, l4 = lane >> 4;
  const int qt = 7 - blockIdx.y;              // heavy tiles dispatch first
  const int bh = blockIdx.x;
  const int b = bh >> 4, h = bh & 15;
  const int qbase = qt*128;
  const int qmin = qbase + w*16;
  const int qg = qmin + l15;                  // this lane's q row
  const float c = 0.12751920700948998f;       // (1/sqrt(128)) * log2(e)
  const float THR = 62.7f;                    // defer-max threshold (2^8 bound)

  const size_t rowq = (size_t)(b*SS + qg)*EE + h*DD;
  bf16x8 qf[4];
  #pragma unroll
  for (int kk = 0; kk < 4; kk++) qf[kk] = ld8(qp + rowq + kk*32 + l4*8);
  #pragma unroll
  for (int kk = 0; kk < 4; kk++) asm volatile("" : "+v"(qf[kk]));

  f32x4 ao[8] = {};                           // O^T: [d = n8*16 + l4*4 + r][q = l15]
  float mi = -3e38f, li = 0.0f;

  const int ntiles = 2*qt + 2;
  const int vcc = lane & 7;

  #pragma unroll
  for (int q = 0; q < 2; q++){
    int r = w*8 + q*4 + (lane>>4);
    g2l16(kp + (size_t)(b*SS + r)*EE + h*DD + (((lane&15) ^ (r&7))<<3),
          &Kl[0][0] + w*1024 + q*512);
    int d = w*16 + q*8 + (lane>>3);
    g2l16(vpT + (size_t)(bh*DD + d)*SS + ((vcc ^ (d&7))<<3),
          &Vl[0][0] + w*1024 + q*512);
  }

  for (int t = 0; t < ntiles; t++){
    const int kv0 = t*64;
    const int buf = t & 1;
    {
      const int kvn = (t + 1 < ntiles) ? kv0 + 64 : kv0;
      #pragma unroll
      for (int q = 0; q < 2; q++){
        int r = w*8 + q*4 + (lane>>4);
        g2l16(kp + (size_t)(b*SS + kvn + r)*EE + h*DD + (((lane&15) ^ (r&7))<<3),
              &Kl[buf^1][0] + w*1024 + q*512);
        int d = w*16 + q*8 + (lane>>3);
        g2l16(vpT + (size_t)(bh*DD + d)*SS + kvn + ((vcc ^ (d&7))<<3),
              &Vl[buf^1][0] + w*1024 + q*512);
      }
    }
    VMC(4);
    BARRIER();

    if (kv0 <= qmin + 15){
      float sv[4][4];
      __builtin_amdgcn_s_setprio(1);
      #pragma unroll
      for (int nt = 0; nt < 4; nt++){
        f32x4 sacc = {};
        #pragma unroll
        for (int kk = 0; kk < 4; kk++){
          bf16x8 kf = ld8(&Kl[buf][0] + (nt*16 + l15)*128 + (((kk*4 + l4) ^ (l15&7))<<3));
          sacc = __builtin_amdgcn_mfma_f32_16x16x32_bf16(kf, qf[kk], sacc, 0, 0, 0);
        }
        #pragma unroll
        for (int r = 0; r < 4; r++) sv[nt][r] = sacc[r];
      }
      __builtin_amdgcn_s_setprio(0);
      if (kv0 + 63 > qmin){
        #pragma unroll
        for (int nt = 0; nt < 4; nt++)
          #pragma unroll
          for (int r = 0; r < 4; r++){
            int kg = kv0 + nt*16 + l4*4 + r;
            if (kg > qg) sv[nt][r] = -3e38f;
          }
      }
      float mx = sv[0][0];
      #pragma unroll
      for (int nt = 0; nt < 4; nt++)
        #pragma unroll
        for (int r = 0; r < 4; r++) mx = fmaxf(mx, sv[nt][r]);
      mx = fmaxf(mx, __shfl_xor(mx, 16));
      mx = fmaxf(mx, __shfl_xor(mx, 32));
      if (__any(mx > mi + THR)){
        float mnew = fmaxf(mi, mx);
        float alpha = __builtin_amdgcn_exp2f((mi - mnew)*c);
        li *= alpha;
        #pragma unroll
        for (int n8 = 0; n8 < 8; n8++) ao[n8] *= alpha;
        mi = mnew;
      }
      const float mnc = mi*c;
      float pout[4][4];
      float rs = 0.0f;
      #pragma unroll
      for (int nt = 0; nt < 4; nt++)
        #pragma unroll
        for (int r = 0; r < 4; r++){
          float pv = __builtin_amdgcn_exp2f(__builtin_fmaf(sv[nt][r], c, -mnc));
          pout[nt][r] = pv; rs += pv;
        }
      rs += __shfl_xor(rs, 16);
      rs += __shfl_xor(rs, 32);
      li += rs;
      #pragma unroll
      for (int kk = 0; kk < 2; kk++){
        #pragma unroll
        for (int ntl = 0; ntl < 2; ntl++){
          int nt = kk*2 + ntl;
          u16x4 pk;
          #pragma unroll
          for (int r = 0; r < 4; r++) pk[r] = f2bf(pout[nt][r]);
          *(u16x4*)(&Pl[w][l15*PLW + ntl*16 + l4*4]) = pk;
        }
        bf16x8 pa = ld8(&Pl[w][l15*PLW + l4*8]);
        __builtin_amdgcn_s_setprio(1);
        #pragma unroll
        for (int n8 = 0; n8 < 8; n8++){
          bf16x8 vf = ld8(&Vl[buf][0] + (n8*16 + l15)*64 + (((kk*4 + l4) ^ (l15&7))<<3));
          ao[n8] = __builtin_amdgcn_mfma_f32_16x16x32_bf16(vf, pa, ao[n8], 0, 0, 0);
        }
        __builtin_amdgcn_s_setprio(0);
      }
    }
    BARRIER();
  }
  asm volatile("s_waitcnt vmcnt(0)" ::: "memory");

  const float inv = 1.0f / li;
  const size_t orow = (size_t)(b*SS + qg)*EE + h*DD;
  #pragma unroll
  for (int n8 = 0; n8 < 8; n8++){
    f32x4 o = ao[n8]*inv;
    *(float4*)(out + orow + n8*16 + l4*4) = __builtin_bit_cast(float4, o);
  }
}

// ---------------- launch ----------------
extern "C" void kernel_launch(void* const* d_in, const int* in_sizes, int n_in,
                              void* d_out, int out_size, void* d_ws, size_t ws_size,
                              hipStream_t stream){
  const float* x    = (const float*)d_in[0];
  const float* Wq   = (const float*)d_in[1];
  const float* Wkvd = (const float*)d_in[2];
  const float* Wku  = (const float*)d_in[3];
  const float* Wvu  = (const float*)d_in[4];
  float* out = (float*)d_out;
  char* ws = (char*)d_ws;

  u16*   xb    = (u16*)  (ws);                 // 33,554,432 B
  u16*   WqT   = (u16*)  (ws +  33554432);     //  8,388,608
  u16*   WkvdT = (u16*)  (ws +  41943040);     //  2,097,152
  u16*   WkuT  = (u16*)  (ws +  44040192);     //  2,097,152  (WvuT adjacent -> 4096xK panel)
  u16*   WvuT  = (u16*)  (ws +  46137344);     //  2,097,152
  float* cosb  = (float*)(ws +  48234496);     //    196,608
  float* sinb  = (float*)(ws +  48431104);     //    196,608
  u16*   qp    = (u16*)  (ws +  48627712);     // 33,554,432
  u16*   ckv   = (u16*)  (ws +  82182144);     //  8,388,608
  u16*   kp    = (u16*)  (ws +  90570752);     // 33,554,432
  u16*   vpT   = (u16*)  (ws + 124125184);     // 33,554,432 (transposed: [bh*128+d][1024])

  prep<<<15552, 256, 0, stream>>>(x, xb, Wq, WqT, Wkvd, WkvdT,
                                  Wku, WkuT, Wvu, WvuT, cosb, sinb);

  // q = x @ Wq  (M=8192, N=2048, K=2048): 256^2 8-phase, 256 blocks, XCD-chunked
  gemm8<<<dim3(EE/256, (BB*SS)/256), 512, 0, stream>>>(xb, WqT, qp, qp,
                                                       EE, EE, EE, EE, 0);
  // c_kv = x @ Wkv_down (N=512, K=2048): 128^2, grid 4x64, XCD-chunked
  gemm_bt<<<dim3(512/128, (BB*SS)/128), 256, 0, stream>>>(xb, WkvdT, ckv, ckv,
                                                          EE, 512, 512, 0);
  // fused k/v up-projection (N=4096, K=512): 128^2, grid 32x64 = 2048 blocks,
  // 4+ blocks/CU co-resident; V half written transposed
  gemm_bt<<<dim3(4096/128, (BB*SS)/128), 256, 0, stream>>>(ckv, WkuT, kp, vpT,
                                                           512, EE, EE, 1);

  rope_apply2<<<dim3((BB*SS*HH)/256, 2), 256, 0, stream>>>(qp, kp, cosb, sinb);

  attn<<<dim3(BB*HH, SS/128), 512, 0, stream>>>(qp, kp, vpT, out);
}

// Round 13
// 287.907 us; speedup vs baseline: 1.7100x; 1.0301x over previous
//
#include <hip/hip_runtime.h>
#include <stdint.h>

typedef unsigned short u16;
typedef __bf16 bf16x8 __attribute__((ext_vector_type(8)));
typedef float    f32x4 __attribute__((ext_vector_type(4)));
typedef unsigned short u16x8 __attribute__((ext_vector_type(8)));
typedef unsigned short u16x4 __attribute__((ext_vector_type(4)));

#define BB 8
#define SS 1024
#define EE 2048
#define HH 16
#define DD 128

__device__ __forceinline__ u16 f2bf(float f){
  union { float f; unsigned u; } v; v.f = f;
  unsigned r = v.u + 0x7FFFu + ((v.u >> 16) & 1u);
  return (u16)(r >> 16);
}
__device__ __forceinline__ float bf2f(u16 h){
  union { unsigned u; float f; } v; v.u = ((unsigned)h) << 16;
  return v.f;
}
__device__ __forceinline__ bf16x8 ld8(const u16* p){
  return __builtin_bit_cast(bf16x8, *(const u16x8*)p);
}

typedef __attribute__((address_space(1))) const unsigned int gas_u32;
typedef __attribute__((address_space(3))) unsigned int las_u32;
__device__ __forceinline__ void g2l16(const u16* g, u16* l){
  __builtin_amdgcn_global_load_lds((gas_u32*)g, (las_u32*)l, 16, 0, 0);
}

#define BARRIER() asm volatile("s_barrier" ::: "memory")
#define VMC(n)    asm volatile("s_waitcnt vmcnt(" #n ")" ::: "memory")

// ---------------- fused prep: cvt + 4 weight transposes + rope tables ----------------
__device__ __forceinline__ void trB(const float* __restrict__ W, u16* __restrict__ Wt,
                                    int K, int N, int bx, int by,
                                    float (*t)[33], int tid){
  int c = tid & 31, r = tid >> 5;
  #pragma unroll
  for (int i = 0; i < 32; i += 8)
    t[r+i][c] = W[(size_t)(by*32 + r + i)*N + bx*32 + c];
  __syncthreads();
  #pragma unroll
  for (int i = 0; i < 32; i += 8)
    Wt[(size_t)(bx*32 + r + i)*K + by*32 + c] = f2bf(t[c][r+i]);
}

__global__ __launch_bounds__(256) void prep(const float* __restrict__ x, u16* __restrict__ xb,
    const float* __restrict__ Wq,   u16* __restrict__ WqT,
    const float* __restrict__ Wkvd, u16* __restrict__ WkvdT,
    const float* __restrict__ Wku,  u16* __restrict__ WkuT,
    const float* __restrict__ Wvu,  u16* __restrict__ WvuT,
    float* __restrict__ cosb, float* __restrict__ sinb){
  __shared__ float t[32][33];
  const int bid = blockIdx.x, tid = threadIdx.x;
  if (bid < 8192){
    int i = (bid*256 + tid)*8;
    float4 v0 = *(const float4*)(x + i);
    float4 v1 = *(const float4*)(x + i + 4);
    u16x8 o;
    o[0]=f2bf(v0.x); o[1]=f2bf(v0.y); o[2]=f2bf(v0.z); o[3]=f2bf(v0.w);
    o[4]=f2bf(v1.x); o[5]=f2bf(v1.y); o[6]=f2bf(v1.z); o[7]=f2bf(v1.w);
    *(u16x8*)(xb + i) = o;
  } else if (bid < 12288){
    int k = bid - 8192;  trB(Wq,   WqT,   EE,  EE,  k & 63, k >> 6, t, tid);
  } else if (bid < 13312){
    int k = bid - 12288; trB(Wkvd, WkvdT, EE,  512, k & 15, k >> 4, t, tid);
  } else if (bid < 14336){
    int k = bid - 13312; trB(Wku,  WkuT,  512, EE,  k & 63, k >> 6, t, tid);
  } else if (bid < 15360){
    int k = bid - 14336; trB(Wvu,  WvuT,  512, EE,  k & 63, k >> 6, t, tid);
  } else {
    int i = (bid - 15360)*256 + tid;
    if (i < SS*48){
      int s = i / 48, j = i % 48;
      float freq = powf(10000.0f, -((float)(2*j)) / 96.0f);
      float e = (float)s * freq;
      cosb[i] = cosf(e);
      sinb[i] = sinf(e);
    }
  }
}

// ---------------- RoPE apply in-place on q and k, one launch ----------------
__global__ __launch_bounds__(256) void rope_apply2(u16* __restrict__ qp,
                                                   u16* __restrict__ kp,
                                                   const float* __restrict__ cosb,
                                                   const float* __restrict__ sinb){
  u16* base = blockIdx.y ? kp : qp;
  int t = blockIdx.x*256 + threadIdx.x;
  int row = t >> 4, h = t & 15, s = row & (SS-1);
  u16* p = base + (size_t)row*EE + h*DD + 32;
  float e[48], o[48];
  #pragma unroll
  for (int c = 0; c < 12; c++){
    u16x8 v = *(const u16x8*)(p + c*8);
    #pragma unroll
    for (int j = 0; j < 4; j++){
      e[c*4 + j] = bf2f(v[2*j]);
      o[c*4 + j] = bf2f(v[2*j+1]);
    }
  }
  u16 ob[96];
  #pragma unroll
  for (int j = 0; j < 48; j++){
    float cs = cosb[s*48 + j], sn = sinb[s*48 + j];
    ob[j]      = f2bf(e[j]*cs - o[j]*sn);
    ob[48 + j] = f2bf(o[j]*cs + e[j]*sn);
  }
  #pragma unroll
  for (int c = 0; c < 12; c++)
    *(u16x8*)(p + c*8) = *(const u16x8*)(ob + c*8);
}

// ---------------- GEMM 256^2, 8-phase, static 2x2 buffers, XCD-chunked ----------------
// C = A[MxK] * Bt[NxK]^T. cols < nsplit -> C0 (stride Nout0); else C1
// (stride Nout1, or transposed V layout when vt=1).
#define AFR(ab, mf, ks) ld8(&AL[ab][wr][((mf)*16 + l15)*64 + ((((ks)*4 + l4) ^ r7) << 3)])
#define BFR(bb, nf, ks) ld8(&BL[bb][wc>>1][(((wc&1)*64 + (nf)*16 + l15))*64 + ((((ks)*4 + l4) ^ r7) << 3)])

#define STAGE_A(ab, h, kt) stage2(aRow, (h), (kt), K, &AL[ab][h][0], wj0)
#define STAGE_A2(ab, kt)   do{ STAGE_A(ab, 0, kt); STAGE_A(ab, 1, kt); }while(0)
#define STAGE_B(bb, h, kt) stage2(bRow, (h), (kt), K, &BL[bb][h][0], wj0)

__device__ __forceinline__ void stage2(const u16* rowbase, int h, int kt, int K,
                                       u16* lds, int wj0){
  const u16* g = rowbase + (size_t)h*128*K + kt*64;
  g2l16(g,               lds + wj0*512);
  g2l16(g + (size_t)8*K, lds + wj0*512 + 512);
}

#define PHASE(ab, q, LOADB, STAGE, DOVM) do{                                       \
  bf16x8 a00 = AFR(ab, 2*(q)  , 0);                                               \
  bf16x8 a01 = AFR(ab, 2*(q)  , 1);                                               \
  bf16x8 a10 = AFR(ab, 2*(q)+1, 0);                                               \
  bf16x8 a11 = AFR(ab, 2*(q)+1, 1);                                               \
  if (LOADB){                                                                      \
    _Pragma("unroll")                                                              \
    for (int nf = 0; nf < 4; nf++){ bq[nf][0]=BFR(ab,nf,0); bq[nf][1]=BFR(ab,nf,1); } \
  }                                                                                \
  STAGE;                                                                           \
  if (DOVM) VMC(4);                                                                \
  BARRIER();                                                                       \
  __builtin_amdgcn_s_setprio(1);                                                   \
  _Pragma("unroll")                                                                \
  for (int nf = 0; nf < 4; nf++){                                                  \
    acc[2*(q)][nf]   = __builtin_amdgcn_mfma_f32_16x16x32_bf16(a00, bq[nf][0], acc[2*(q)][nf],0,0,0);   \
    acc[2*(q)+1][nf] = __builtin_amdgcn_mfma_f32_16x16x32_bf16(a10, bq[nf][0], acc[2*(q)+1][nf],0,0,0); \
  }                                                                                \
  _Pragma("unroll")                                                                \
  for (int nf = 0; nf < 4; nf++){                                                  \
    acc[2*(q)][nf]   = __builtin_amdgcn_mfma_f32_16x16x32_bf16(a01, bq[nf][1], acc[2*(q)][nf],0,0,0);   \
    acc[2*(q)+1][nf] = __builtin_amdgcn_mfma_f32_16x16x32_bf16(a11, bq[nf][1], acc[2*(q)+1][nf],0,0,0); \
  }                                                                                \
  __builtin_amdgcn_s_setprio(0);                                                   \
  BARRIER();                                                                       \
  __builtin_amdgcn_sched_barrier(0);                                               \
}while(0)

__global__ __launch_bounds__(512, 2) void gemm8(const u16* __restrict__ A,
    const u16* __restrict__ Bt, u16* __restrict__ C0, u16* __restrict__ C1,
    int K, int Nout0, int Nout1, int nsplit, int vt){
  __shared__ u16 AL[2][2][128*64];   // 64 KB
  __shared__ u16 BL[2][2][128*64];   // 64 KB -> 128 KiB total
  const int tid = threadIdx.x, lane = tid & 63, w = tid >> 6;
  const int wr = w >> 2, wc = w & 3;
  const int l15 = lane & 15, l4 = lane >> 4;
  const int r7 = l15 & 7;
  // XCD chunk swizzle (general): per XCD, bn fastest, then bm chunks.
  // Requires gridDim.y % 8 == 0; works for any gridDim.x.
  const int nbx = gridDim.x;
  const int id  = blockIdx.y * nbx + blockIdx.x;
  const int xcd = id & 7, j = id >> 3;
  const int rpx = gridDim.y >> 3;                  // bm rows per XCD
  const int bn  = (j % nbx) * 256;
  const int bm  = (xcd*rpx + (j / nbx)) * 256;
  const int wj0 = w*2;
  const int cswz = (lane & 7) ^ (lane >> 3);
  const u16* aRow = A  + (size_t)(bm + wj0*8 + (lane>>3))*K + cswz*8;
  const u16* bRow = Bt + (size_t)(bn + wj0*8 + (lane>>3))*K + cswz*8;

  const int nkt = K >> 6;
  const int niter = nkt >> 1;

  // prologue: A(0)->A[0], B(0)->B[0], B(1)->B[1]; retire A(0),B(0); B(1) in flight
  STAGE_A2(0, 0);
  STAGE_B(0, 0, 0); STAGE_B(0, 1, 0);
  STAGE_B(1, 0, 1); STAGE_B(1, 1, 1);
  VMC(4);
  BARRIER();

  f32x4 acc[8][4] = {};
  bf16x8 bq[4][2];

  for (int it = 0; it < niter; ++it){
    const int kt1 = 2*it + 1;
    int kt2 = 2*it + 2; if (kt2 >= nkt) kt2 -= nkt;   // wrap: harmless re-read
    int kt3 = 2*it + 3; if (kt3 >= nkt) kt3 -= nkt;
    // tile 2it (A[0], B[0])
    PHASE(0, 0, 1, STAGE_A2(1, kt1),    0);
    PHASE(0, 1, 0, STAGE_B(0, 0, kt2),  0);
    PHASE(0, 2, 0, STAGE_B(0, 1, kt2),  0);
    PHASE(0, 3, 0, ;,                   1);   // VMC(4): A(2it+1),B(2it+1) ready
    // tile 2it+1 (A[1], B[1])
    PHASE(1, 0, 1, STAGE_A2(0, kt2),    0);
    PHASE(1, 1, 0, STAGE_B(1, 0, kt3),  0);
    PHASE(1, 2, 0, STAGE_B(1, 1, kt3),  0);
    PHASE(1, 3, 0, ;,                   1);   // VMC(4): A(2it+2),B(2it+2) ready
  }
  asm volatile("s_waitcnt vmcnt(0)" ::: "memory");

  if (vt && bn >= nsplit){
    // transposed store: C1 is vpT[(b*16 + head)*128 + d][1024 s]
    const int bcol = bn - nsplit;
    #pragma unroll
    for (int mf = 0; mf < 8; mf++)
      #pragma unroll
      for (int nf = 0; nf < 4; nf++){
        int row0 = bm + wr*128 + mf*16 + l4*4;
        int col  = bcol + wc*64 + nf*16 + l15;
        int bh = (row0 >> 10)*16 + (col >> 7);
        int d  = col & 127;
        int s  = row0 & 1023;
        u16x4 pk;
        #pragma unroll
        for (int r = 0; r < 4; r++) pk[r] = f2bf(acc[mf][nf][r]);
        *(u16x4*)(C1 + (((size_t)(bh*128 + d)) << 10) + s) = pk;
      }
  } else {
    u16* Cd = (bn < nsplit) ? C0 : C1;
    const int No = (bn < nsplit) ? Nout0 : Nout1;
    const int bcol = (bn < nsplit) ? bn : bn - nsplit;
    #pragma unroll
    for (int mf = 0; mf < 8; mf++)
      #pragma unroll
      for (int nf = 0; nf < 4; nf++)
        #pragma unroll
        for (int r = 0; r < 4; r++){
          int row = bm + wr*128 + mf*16 + l4*4 + r;
          int col = bcol + wc*64 + nf*16 + l15;
          Cd[(size_t)row*No + col] = f2bf(acc[mf][nf][r]);
        }
  }
}

// ---------------- Flash attention v6: swapped-operand in-register softmax ----------------
#define PLW 40   // P row stride in u16 (80 B): bank stride 20 -> 2-way max, 16B-aligned

__global__ __launch_bounds__(512) void attn(const u16* __restrict__ qp,
                                            const u16* __restrict__ kp,
                                            const u16* __restrict__ vpT,
                                            float* __restrict__ out){
  __shared__ u16 Kl[2][64*128];   // 32768 B
  __shared__ u16 Vl[2][128*64];   // 32768 B
  __shared__ u16 Pl[8][16*PLW];   // 10240 B  -> total 75776 B (2 blocks/CU)
  const int tid = threadIdx.x, lane = tid & 63, w = tid >> 6;
  const int l15 = lane & 15, l4 = lane >> 4;
  const int qt = 7 - blockIdx.y;              // heavy tiles dispatch first
  const int bh = blockIdx.x;
  const int b = bh >> 4, h = bh & 15;
  const int qbase = qt*128;
  const int qmin = qbase + w*16;
  const int qg = qmin + l15;                  // this lane's q row
  const float c = 0.12751920700948998f;       // (1/sqrt(128)) * log2(e)
  const float THR = 62.7f;                    // defer-max threshold (2^8 bound)

  const size_t rowq = (size_t)(b*SS + qg)*EE + h*DD;
  bf16x8 qf[4];
  #pragma unroll
  for (int kk = 0; kk < 4; kk++) qf[kk] = ld8(qp + rowq + kk*32 + l4*8);
  #pragma unroll
  for (int kk = 0; kk < 4; kk++) asm volatile("" : "+v"(qf[kk]));

  f32x4 ao[8] = {};                           // O^T: [d = n8*16 + l4*4 + r][q = l15]
  float mi = -3e38f, li = 0.0f;

  const int ntiles = 2*qt + 2;
  const int vcc = lane & 7;

  #pragma unroll
  for (int q = 0; q < 2; q++){
    int r = w*8 + q*4 + (lane>>4);
    g2l16(kp + (size_t)(b*SS + r)*EE + h*DD + (((lane&15) ^ (r&7))<<3),
          &Kl[0][0] + w*1024 + q*512);
    int d = w*16 + q*8 + (lane>>3);
    g2l16(vpT + (size_t)(bh*DD + d)*SS + ((vcc ^ (d&7))<<3),
          &Vl[0][0] + w*1024 + q*512);
  }

  for (int t = 0; t < ntiles; t++){
    const int kv0 = t*64;
    const int buf = t & 1;
    {
      const int kvn = (t + 1 < ntiles) ? kv0 + 64 : kv0;
      #pragma unroll
      for (int q = 0; q < 2; q++){
        int r = w*8 + q*4 + (lane>>4);
        g2l16(kp + (size_t)(b*SS + kvn + r)*EE + h*DD + (((lane&15) ^ (r&7))<<3),
              &Kl[buf^1][0] + w*1024 + q*512);
        int d = w*16 + q*8 + (lane>>3);
        g2l16(vpT + (size_t)(bh*DD + d)*SS + kvn + ((vcc ^ (d&7))<<3),
              &Vl[buf^1][0] + w*1024 + q*512);
      }
    }
    VMC(4);
    BARRIER();

    if (kv0 <= qmin + 15){
      float sv[4][4];
      __builtin_amdgcn_s_setprio(1);
      #pragma unroll
      for (int nt = 0; nt < 4; nt++){
        f32x4 sacc = {};
        #pragma unroll
        for (int kk = 0; kk < 4; kk++){
          bf16x8 kf = ld8(&Kl[buf][0] + (nt*16 + l15)*128 + (((kk*4 + l4) ^ (l15&7))<<3));
          sacc = __builtin_amdgcn_mfma_f32_16x16x32_bf16(kf, qf[kk], sacc, 0, 0, 0);
        }
        #pragma unroll
        for (int r = 0; r < 4; r++) sv[nt][r] = sacc[r];
      }
      __builtin_amdgcn_s_setprio(0);
      if (kv0 + 63 > qmin){
        #pragma unroll
        for (int nt = 0; nt < 4; nt++)
          #pragma unroll
          for (int r = 0; r < 4; r++){
            int kg = kv0 + nt*16 + l4*4 + r;
            if (kg > qg) sv[nt][r] = -3e38f;
          }
      }
      float mx = sv[0][0];
      #pragma unroll
      for (int nt = 0; nt < 4; nt++)
        #pragma unroll
        for (int r = 0; r < 4; r++) mx = fmaxf(mx, sv[nt][r]);
      mx = fmaxf(mx, __shfl_xor(mx, 16));
      mx = fmaxf(mx, __shfl_xor(mx, 32));
      if (__any(mx > mi + THR)){
        float mnew = fmaxf(mi, mx);
        float alpha = __builtin_amdgcn_exp2f((mi - mnew)*c);
        li *= alpha;
        #pragma unroll
        for (int n8 = 0; n8 < 8; n8++) ao[n8] *= alpha;
        mi = mnew;
      }
      const float mnc = mi*c;
      float pout[4][4];
      float rs = 0.0f;
      #pragma unroll
      for (int nt = 0; nt < 4; nt++)
        #pragma unroll
        for (int r = 0; r < 4; r++){
          float pv = __builtin_amdgcn_exp2f(__builtin_fmaf(sv[nt][r], c, -mnc));
          pout[nt][r] = pv; rs += pv;
        }
      rs += __shfl_xor(rs, 16);
      rs += __shfl_xor(rs, 32);
      li += rs;
      #pragma unroll
      for (int kk = 0; kk < 2; kk++){
        #pragma unroll
        for (int ntl = 0; ntl < 2; ntl++){
          int nt = kk*2 + ntl;
          u16x4 pk;
          #pragma unroll
          for (int r = 0; r < 4; r++) pk[r] = f2bf(pout[nt][r]);
          *(u16x4*)(&Pl[w][l15*PLW + ntl*16 + l4*4]) = pk;
        }
        bf16x8 pa = ld8(&Pl[w][l15*PLW + l4*8]);
        __builtin_amdgcn_s_setprio(1);
        #pragma unroll
        for (int n8 = 0; n8 < 8; n8++){
          bf16x8 vf = ld8(&Vl[buf][0] + (n8*16 + l15)*64 + (((kk*4 + l4) ^ (l15&7))<<3));
          ao[n8] = __builtin_amdgcn_mfma_f32_16x16x32_bf16(vf, pa, ao[n8], 0, 0, 0);
        }
        __builtin_amdgcn_s_setprio(0);
      }
    }
    BARRIER();
  }
  asm volatile("s_waitcnt vmcnt(0)" ::: "memory");

  const float inv = 1.0f / li;
  const size_t orow = (size_t)(b*SS + qg)*EE + h*DD;
  #pragma unroll
  for (int n8 = 0; n8 < 8; n8++){
    f32x4 o = ao[n8]*inv;
    *(float4*)(out + orow + n8*16 + l4*4) = __builtin_bit_cast(float4, o);
  }
}

// ---------------- launch ----------------
extern "C" void kernel_launch(void* const* d_in, const int* in_sizes, int n_in,
                              void* d_out, int out_size, void* d_ws, size_t ws_size,
                              hipStream_t stream){
  const float* x    = (const float*)d_in[0];
  const float* Wq   = (const float*)d_in[1];
  const float* Wkvd = (const float*)d_in[2];
  const float* Wku  = (const float*)d_in[3];
  const float* Wvu  = (const float*)d_in[4];
  float* out = (float*)d_out;
  char* ws = (char*)d_ws;

  u16*   xb    = (u16*)  (ws);                 // 33,554,432 B
  u16*   WqT   = (u16*)  (ws +  33554432);     //  8,388,608  (WkvdT adjacent -> 2560xK panel)
  u16*   WkvdT = (u16*)  (ws +  41943040);     //  2,097,152
  u16*   WkuT  = (u16*)  (ws +  44040192);     //  2,097,152  (WvuT adjacent -> 4096xK panel)
  u16*   WvuT  = (u16*)  (ws +  46137344);     //  2,097,152
  float* cosb  = (float*)(ws +  48234496);     //    196,608
  float* sinb  = (float*)(ws +  48431104);     //    196,608
  u16*   qp    = (u16*)  (ws +  48627712);     // 33,554,432
  u16*   ckv   = (u16*)  (ws +  82182144);     //  8,388,608
  u16*   kp    = (u16*)  (ws +  90570752);     // 33,554,432
  u16*   vpT   = (u16*)  (ws + 124125184);     // 33,554,432 (transposed: [bh*128+d][1024])

  prep<<<15552, 256, 0, stream>>>(x, xb, Wq, WqT, Wkvd, WkvdT,
                                  Wku, WkuT, Wvu, WvuT, cosb, sinb);

  // fused q + c_kv projection: Bt = [WqT; WkvdT] (N=2560, K=2048), grid (10,32)
  gemm8<<<dim3(2560/256, (BB*SS)/256), 512, 0, stream>>>(xb, WqT, qp, ckv,
                                                         EE, EE, 512, EE, 0);
  // fused k/v up-projection (N=4096, K=512), grid (16,32); V half written transposed
  gemm8<<<dim3(4096/256, (BB*SS)/256), 512, 0, stream>>>(ckv, WkuT, kp, vpT,
                                                         512, EE, 0, EE, 1);

  rope_apply2<<<dim3((BB*SS*HH)/256, 2), 256, 0, stream>>>(qp, kp, cosb, sinb);

  attn<<<dim3(BB*HH, SS/128), 512, 0, stream>>>(qp, kp, vpT, out);
}

// Round 14
// 280.965 us; speedup vs baseline: 1.7522x; 1.0247x over previous
//
#include <hip/hip_runtime.h>
#include <stdint.h>

typedef unsigned short u16;
typedef __bf16 bf16x8 __attribute__((ext_vector_type(8)));
typedef float    f32x4 __attribute__((ext_vector_type(4)));
typedef unsigned short u16x8 __attribute__((ext_vector_type(8)));
typedef unsigned short u16x4 __attribute__((ext_vector_type(4)));

#define BB 8
#define SS 1024
#define EE 2048
#define HH 16
#define DD 128

__device__ __forceinline__ u16 f2bf(float f){
  union { float f; unsigned u; } v; v.f = f;
  unsigned r = v.u + 0x7FFFu + ((v.u >> 16) & 1u);
  return (u16)(r >> 16);
}
__device__ __forceinline__ float bf2f(u16 h){
  union { unsigned u; float f; } v; v.u = ((unsigned)h) << 16;
  return v.f;
}
__device__ __forceinline__ bf16x8 ld8(const u16* p){
  return __builtin_bit_cast(bf16x8, *(const u16x8*)p);
}

typedef __attribute__((address_space(1))) const unsigned int gas_u32;
typedef __attribute__((address_space(3))) unsigned int las_u32;
__device__ __forceinline__ void g2l16(const u16* g, u16* l){
  __builtin_amdgcn_global_load_lds((gas_u32*)g, (las_u32*)l, 16, 0, 0);
}

#define BARRIER() asm volatile("s_barrier" ::: "memory")
#define VMC(n)    asm volatile("s_waitcnt vmcnt(" #n ")" ::: "memory")

// ---------------- fused prep: cvt + 4 weight transposes + rope tables ----------------
__device__ __forceinline__ void trB(const float* __restrict__ W, u16* __restrict__ Wt,
                                    int K, int N, int bx, int by,
                                    float (*t)[33], int tid){
  int c = tid & 31, r = tid >> 5;
  #pragma unroll
  for (int i = 0; i < 32; i += 8)
    t[r+i][c] = W[(size_t)(by*32 + r + i)*N + bx*32 + c];
  __syncthreads();
  #pragma unroll
  for (int i = 0; i < 32; i += 8)
    Wt[(size_t)(bx*32 + r + i)*K + by*32 + c] = f2bf(t[c][r+i]);
}

__global__ __launch_bounds__(256) void prep(const float* __restrict__ x, u16* __restrict__ xb,
    const float* __restrict__ Wq,   u16* __restrict__ WqT,
    const float* __restrict__ Wkvd, u16* __restrict__ WkvdT,
    const float* __restrict__ Wku,  u16* __restrict__ WkuT,
    const float* __restrict__ Wvu,  u16* __restrict__ WvuT,
    float* __restrict__ cosb, float* __restrict__ sinb){
  __shared__ float t[32][33];
  const int bid = blockIdx.x, tid = threadIdx.x;
  if (bid < 8192){
    int i = (bid*256 + tid)*8;
    float4 v0 = *(const float4*)(x + i);
    float4 v1 = *(const float4*)(x + i + 4);
    u16x8 o;
    o[0]=f2bf(v0.x); o[1]=f2bf(v0.y); o[2]=f2bf(v0.z); o[3]=f2bf(v0.w);
    o[4]=f2bf(v1.x); o[5]=f2bf(v1.y); o[6]=f2bf(v1.z); o[7]=f2bf(v1.w);
    *(u16x8*)(xb + i) = o;
  } else if (bid < 12288){
    int k = bid - 8192;  trB(Wq,   WqT,   EE,  EE,  k & 63, k >> 6, t, tid);
  } else if (bid < 13312){
    int k = bid - 12288; trB(Wkvd, WkvdT, EE,  512, k & 15, k >> 4, t, tid);
  } else if (bid < 14336){
    int k = bid - 13312; trB(Wku,  WkuT,  512, EE,  k & 63, k >> 6, t, tid);
  } else if (bid < 15360){
    int k = bid - 14336; trB(Wvu,  WvuT,  512, EE,  k & 63, k >> 6, t, tid);
  } else {
    int i = (bid - 15360)*256 + tid;
    if (i < SS*48){
      int s = i / 48, j = i % 48;
      float freq = powf(10000.0f, -((float)(2*j)) / 96.0f);
      float e = (float)s * freq;
      cosb[i] = cosf(e);
      sinb[i] = sinf(e);
    }
  }
}

// ---------------- RoPE apply in-place on q and k, one launch ----------------
__global__ __launch_bounds__(256) void rope_apply2(u16* __restrict__ qp,
                                                   u16* __restrict__ kp,
                                                   const float* __restrict__ cosb,
                                                   const float* __restrict__ sinb){
  u16* base = blockIdx.y ? kp : qp;
  int t = blockIdx.x*256 + threadIdx.x;
  int row = t >> 4, h = t & 15, s = row & (SS-1);
  u16* p = base + (size_t)row*EE + h*DD + 32;
  float e[48], o[48];
  #pragma unroll
  for (int c = 0; c < 12; c++){
    u16x8 v = *(const u16x8*)(p + c*8);
    #pragma unroll
    for (int j = 0; j < 4; j++){
      e[c*4 + j] = bf2f(v[2*j]);
      o[c*4 + j] = bf2f(v[2*j+1]);
    }
  }
  u16 ob[96];
  #pragma unroll
  for (int j = 0; j < 48; j++){
    float cs = cosb[s*48 + j], sn = sinb[s*48 + j];
    ob[j]      = f2bf(e[j]*cs - o[j]*sn);
    ob[48 + j] = f2bf(o[j]*cs + e[j]*sn);
  }
  #pragma unroll
  for (int c = 0; c < 12; c++)
    *(u16x8*)(p + c*8) = *(const u16x8*)(ob + c*8);
}

// ---------------- GEMM 128^2 (m97 structure) for N=512, XCD-chunked (R10) ----------------
__global__ __launch_bounds__(256) void gemm_bt(const u16* __restrict__ A,
    const u16* __restrict__ Bt, u16* __restrict__ C, int M, int N, int K){
  __shared__ u16 Al[128*32];
  __shared__ u16 Bl[128*32];
  const int tid = threadIdx.x;
  const int lane = tid & 63, w = tid >> 6;
  const int wr = w >> 1, wc = w & 1;
  const int l15 = lane & 15, l4 = lane >> 4;
  const int id = blockIdx.y * 4 + blockIdx.x;
  const int xcd = id & 7, j = id >> 3;
  const int bm = (xcd*8 + (j >> 2)) * 128;
  const int bn = (j & 3) * 128;
  const int srow = tid >> 2;
  const int skc  = (tid & 3) * 8;
  const u16* ga = A  + (size_t)(bm + srow)*K + skc;
  const u16* gb = Bt + (size_t)(bn + srow)*K + skc;
  u16* la = Al + w*512;
  u16* lb = Bl + w*512;
  f32x4 acc[4][4] = {};
  for (int k0 = 0; k0 < K; k0 += 32){
    __syncthreads();
    g2l16(ga + k0,          la);
    g2l16(ga + 64*K + k0,   la + 2048);
    g2l16(gb + k0,          lb);
    g2l16(gb + 64*K + k0,   lb + 2048);
    __syncthreads();
    bf16x8 af[4], bfr[4];
    #pragma unroll
    for (int m = 0; m < 4; m++) af[m]  = ld8(Al + (wr*64 + m*16 + l15)*32 + l4*8);
    #pragma unroll
    for (int n = 0; n < 4; n++) bfr[n] = ld8(Bl + (wc*64 + n*16 + l15)*32 + l4*8);
    #pragma unroll
    for (int m = 0; m < 4; m++)
      #pragma unroll
      for (int n = 0; n < 4; n++)
        acc[m][n] = __builtin_amdgcn_mfma_f32_16x16x32_bf16(af[m], bfr[n], acc[m][n], 0, 0, 0);
  }
  #pragma unroll
  for (int m = 0; m < 4; m++)
    #pragma unroll
    for (int n = 0; n < 4; n++)
      #pragma unroll
      for (int r = 0; r < 4; r++){
        int row = bm + wr*64 + m*16 + l4*4 + r;
        int col = bn + wc*64 + n*16 + l15;
        C[(size_t)row*N + col] = f2bf(acc[m][n][r]);
      }
}

// ---------------- GEMM 256^2, 8-phase, static 2x2 buffers, XCD-chunked ----------------
// NLOOP compile-time: number of bn tiles per block (stride gridDim.x*256).
// cols < nsplit -> C0 (stride Nout0); else C1 (stride Nout1, transposed V when vt=1).
#define AFR(ab, mf, ks) ld8(&AL[ab][wr][((mf)*16 + l15)*64 + ((((ks)*4 + l4) ^ r7) << 3)])
#define BFR(bb, nf, ks) ld8(&BL[bb][wc>>1][(((wc&1)*64 + (nf)*16 + l15))*64 + ((((ks)*4 + l4) ^ r7) << 3)])

#define STAGE_A(ab, h, kt) stage2(aRow, (h), (kt), K, &AL[ab][h][0], wj0)
#define STAGE_A2(ab, kt)   do{ STAGE_A(ab, 0, kt); STAGE_A(ab, 1, kt); }while(0)
#define STAGE_B(bb, h, kt) stage2(bRow, (h), (kt), K, &BL[bb][h][0], wj0)

__device__ __forceinline__ void stage2(const u16* rowbase, int h, int kt, int K,
                                       u16* lds, int wj0){
  const u16* g = rowbase + (size_t)h*128*K + kt*64;
  g2l16(g,               lds + wj0*512);
  g2l16(g + (size_t)8*K, lds + wj0*512 + 512);
}

#define PHASE(ab, q, LOADB, STAGE, DOVM) do{                                       \
  bf16x8 a00 = AFR(ab, 2*(q)  , 0);                                               \
  bf16x8 a01 = AFR(ab, 2*(q)  , 1);                                               \
  bf16x8 a10 = AFR(ab, 2*(q)+1, 0);                                               \
  bf16x8 a11 = AFR(ab, 2*(q)+1, 1);                                               \
  if (LOADB){                                                                      \
    _Pragma("unroll")                                                              \
    for (int nf = 0; nf < 4; nf++){ bq[nf][0]=BFR(ab,nf,0); bq[nf][1]=BFR(ab,nf,1); } \
  }                                                                                \
  STAGE;                                                                           \
  if (DOVM) VMC(4);                                                                \
  BARRIER();                                                                       \
  __builtin_amdgcn_s_setprio(1);                                                   \
  _Pragma("unroll")                                                                \
  for (int nf = 0; nf < 4; nf++){                                                  \
    acc[2*(q)][nf]   = __builtin_amdgcn_mfma_f32_16x16x32_bf16(a00, bq[nf][0], acc[2*(q)][nf],0,0,0);   \
    acc[2*(q)+1][nf] = __builtin_amdgcn_mfma_f32_16x16x32_bf16(a10, bq[nf][0], acc[2*(q)+1][nf],0,0,0); \
  }                                                                                \
  _Pragma("unroll")                                                                \
  for (int nf = 0; nf < 4; nf++){                                                  \
    acc[2*(q)][nf]   = __builtin_amdgcn_mfma_f32_16x16x32_bf16(a01, bq[nf][1], acc[2*(q)][nf],0,0,0);   \
    acc[2*(q)+1][nf] = __builtin_amdgcn_mfma_f32_16x16x32_bf16(a11, bq[nf][1], acc[2*(q)+1][nf],0,0,0); \
  }                                                                                \
  __builtin_amdgcn_s_setprio(0);                                                   \
  BARRIER();                                                                       \
  __builtin_amdgcn_sched_barrier(0);                                               \
}while(0)

template<int NLOOP>
__global__ __launch_bounds__(512, 2) void gemm8(const u16* __restrict__ A,
    const u16* __restrict__ Bt, u16* __restrict__ C0, u16* __restrict__ C1,
    int K, int Nout0, int Nout1, int nsplit, int vt){
  __shared__ u16 AL[2][2][128*64];   // 64 KB
  __shared__ u16 BL[2][2][128*64];   // 64 KB -> 128 KiB total
  const int tid = threadIdx.x, lane = tid & 63, w = tid >> 6;
  const int wr = w >> 2, wc = w & 3;
  const int l15 = lane & 15, l4 = lane >> 4;
  const int r7 = l15 & 7;
  // XCD chunk swizzle: per XCD, bn fastest, then bm chunks (gridDim.y % 8 == 0)
  const int nbx = gridDim.x;
  const int id  = blockIdx.y * nbx + blockIdx.x;
  const int xcd = id & 7, j = id >> 3;
  const int rpx = gridDim.y >> 3;
  const int bn0 = (j % nbx) * 256;
  const int bm  = (xcd*rpx + (j / nbx)) * 256;
  const int wj0 = w*2;
  const int cswz = (lane & 7) ^ (lane >> 3);
  const u16* aRow = A + (size_t)(bm + wj0*8 + (lane>>3))*K + cswz*8;

  const int nkt = K >> 6;
  const int niter = nkt >> 1;

  #pragma unroll
  for (int t2 = 0; t2 < NLOOP; t2++){
    const int bn = bn0 + t2 * nbx * 256;
    const u16* bRow = Bt + (size_t)(bn + wj0*8 + (lane>>3))*K + cswz*8;

    // prologue: A(0)->A[0], B(0)->B[0], B(1)->B[1]; retire A(0),B(0); B(1) in flight
    STAGE_A2(0, 0);
    STAGE_B(0, 0, 0); STAGE_B(0, 1, 0);
    STAGE_B(1, 0, 1); STAGE_B(1, 1, 1);
    VMC(4);
    BARRIER();

    f32x4 acc[8][4] = {};
    bf16x8 bq[4][2];

    for (int it = 0; it < niter; ++it){
      const int kt1 = 2*it + 1;
      int kt2 = 2*it + 2; if (kt2 >= nkt) kt2 -= nkt;   // wrap: harmless re-read
      int kt3 = 2*it + 3; if (kt3 >= nkt) kt3 -= nkt;
      // tile 2it (A[0], B[0])
      PHASE(0, 0, 1, STAGE_A2(1, kt1),    0);
      PHASE(0, 1, 0, STAGE_B(0, 0, kt2),  0);
      PHASE(0, 2, 0, STAGE_B(0, 1, kt2),  0);
      PHASE(0, 3, 0, ;,                   1);   // VMC(4): A(2it+1),B(2it+1) ready
      // tile 2it+1 (A[1], B[1])
      PHASE(1, 0, 1, STAGE_A2(0, kt2),    0);
      PHASE(1, 1, 0, STAGE_B(1, 0, kt3),  0);
      PHASE(1, 2, 0, STAGE_B(1, 1, kt3),  0);
      PHASE(1, 3, 0, ;,                   1);   // VMC(4): A(2it+2),B(2it+2) ready
    }
    asm volatile("s_waitcnt vmcnt(0)" ::: "memory");

    if (vt && bn >= nsplit){
      // transposed store: C1 is vpT[(b*16 + head)*128 + d][1024 s]
      const int bcol = bn - nsplit;
      #pragma unroll
      for (int mf = 0; mf < 8; mf++)
        #pragma unroll
        for (int nf = 0; nf < 4; nf++){
          int row0 = bm + wr*128 + mf*16 + l4*4;
          int col  = bcol + wc*64 + nf*16 + l15;
          int bh = (row0 >> 10)*16 + (col >> 7);
          int d  = col & 127;
          int s  = row0 & 1023;
          u16x4 pk;
          #pragma unroll
          for (int r = 0; r < 4; r++) pk[r] = f2bf(acc[mf][nf][r]);
          *(u16x4*)(C1 + (((size_t)(bh*128 + d)) << 10) + s) = pk;
        }
    } else {
      u16* Cd = (bn < nsplit) ? C0 : C1;
      const int No = (bn < nsplit) ? Nout0 : Nout1;
      const int bcol = (bn < nsplit) ? bn : bn - nsplit;
      #pragma unroll
      for (int mf = 0; mf < 8; mf++)
        #pragma unroll
        for (int nf = 0; nf < 4; nf++)
          #pragma unroll
          for (int r = 0; r < 4; r++){
            int row = bm + wr*128 + mf*16 + l4*4 + r;
            int col = bcol + wc*64 + nf*16 + l15;
            Cd[(size_t)row*No + col] = f2bf(acc[mf][nf][r]);
          }
    }
  }
}

// ---------------- Flash attention v6: swapped-operand in-register softmax ----------------
#define PLW 40   // P row stride in u16 (80 B): bank stride 20 -> 2-way max, 16B-aligned

__global__ __launch_bounds__(512) void attn(const u16* __restrict__ qp,
                                            const u16* __restrict__ kp,
                                            const u16* __restrict__ vpT,
                                            float* __restrict__ out){
  __shared__ u16 Kl[2][64*128];   // 32768 B
  __shared__ u16 Vl[2][128*64];   // 32768 B
  __shared__ u16 Pl[8][16*PLW];   // 10240 B  -> total 75776 B (2 blocks/CU)
  const int tid = threadIdx.x, lane = tid & 63, w = tid >> 6;
  const int l15 = lane & 15, l4 = lane >> 4;
  const int qt = 7 - blockIdx.y;              // heavy tiles dispatch first
  const int bh = blockIdx.x;
  const int b = bh >> 4, h = bh & 15;
  const int qbase = qt*128;
  const int qmin = qbase + w*16;
  const int qg = qmin + l15;                  // this lane's q row
  const float c = 0.12751920700948998f;       // (1/sqrt(128)) * log2(e)
  const float THR = 62.7f;                    // defer-max threshold (2^8 bound)

  const size_t rowq = (size_t)(b*SS + qg)*EE + h*DD;
  bf16x8 qf[4];
  #pragma unroll
  for (int kk = 0; kk < 4; kk++) qf[kk] = ld8(qp + rowq + kk*32 + l4*8);
  #pragma unroll
  for (int kk = 0; kk < 4; kk++) asm volatile("" : "+v"(qf[kk]));

  f32x4 ao[8] = {};                           // O^T: [d = n8*16 + l4*4 + r][q = l15]
  float mi = -3e38f, li = 0.0f;

  const int ntiles = 2*qt + 2;
  const int vcc = lane & 7;

  #pragma unroll
  for (int q = 0; q < 2; q++){
    int r = w*8 + q*4 + (lane>>4);
    g2l16(kp + (size_t)(b*SS + r)*EE + h*DD + (((lane&15) ^ (r&7))<<3),
          &Kl[0][0] + w*1024 + q*512);
    int d = w*16 + q*8 + (lane>>3);
    g2l16(vpT + (size_t)(bh*DD + d)*SS + ((vcc ^ (d&7))<<3),
          &Vl[0][0] + w*1024 + q*512);
  }

  for (int t = 0; t < ntiles; t++){
    const int kv0 = t*64;
    const int buf = t & 1;
    {
      const int kvn = (t + 1 < ntiles) ? kv0 + 64 : kv0;
      #pragma unroll
      for (int q = 0; q < 2; q++){
        int r = w*8 + q*4 + (lane>>4);
        g2l16(kp + (size_t)(b*SS + kvn + r)*EE + h*DD + (((lane&15) ^ (r&7))<<3),
              &Kl[buf^1][0] + w*1024 + q*512);
        int d = w*16 + q*8 + (lane>>3);
        g2l16(vpT + (size_t)(bh*DD + d)*SS + kvn + ((vcc ^ (d&7))<<3),
              &Vl[buf^1][0] + w*1024 + q*512);
      }
    }
    VMC(4);
    BARRIER();

    if (kv0 <= qmin + 15){
      float sv[4][4];
      __builtin_amdgcn_s_setprio(1);
      #pragma unroll
      for (int nt = 0; nt < 4; nt++){
        f32x4 sacc = {};
        #pragma unroll
        for (int kk = 0; kk < 4; kk++){
          bf16x8 kf = ld8(&Kl[buf][0] + (nt*16 + l15)*128 + (((kk*4 + l4) ^ (l15&7))<<3));
          sacc = __builtin_amdgcn_mfma_f32_16x16x32_bf16(kf, qf[kk], sacc, 0, 0, 0);
        }
        #pragma unroll
        for (int r = 0; r < 4; r++) sv[nt][r] = sacc[r];
      }
      __builtin_amdgcn_s_setprio(0);
      if (kv0 + 63 > qmin){
        #pragma unroll
        for (int nt = 0; nt < 4; nt++)
          #pragma unroll
          for (int r = 0; r < 4; r++){
            int kg = kv0 + nt*16 + l4*4 + r;
            if (kg > qg) sv[nt][r] = -3e38f;
          }
      }
      float mx = sv[0][0];
      #pragma unroll
      for (int nt = 0; nt < 4; nt++)
        #pragma unroll
        for (int r = 0; r < 4; r++) mx = fmaxf(mx, sv[nt][r]);
      mx = fmaxf(mx, __shfl_xor(mx, 16));
      mx = fmaxf(mx, __shfl_xor(mx, 32));
      if (__any(mx > mi + THR)){
        float mnew = fmaxf(mi, mx);
        float alpha = __builtin_amdgcn_exp2f((mi - mnew)*c);
        li *= alpha;
        #pragma unroll
        for (int n8 = 0; n8 < 8; n8++) ao[n8] *= alpha;
        mi = mnew;
      }
      const float mnc = mi*c;
      float pout[4][4];
      float rs = 0.0f;
      #pragma unroll
      for (int nt = 0; nt < 4; nt++)
        #pragma unroll
        for (int r = 0; r < 4; r++){
          float pv = __builtin_amdgcn_exp2f(__builtin_fmaf(sv[nt][r], c, -mnc));
          pout[nt][r] = pv; rs += pv;
        }
      rs += __shfl_xor(rs, 16);
      rs += __shfl_xor(rs, 32);
      li += rs;
      #pragma unroll
      for (int kk = 0; kk < 2; kk++){
        #pragma unroll
        for (int ntl = 0; ntl < 2; ntl++){
          int nt = kk*2 + ntl;
          u16x4 pk;
          #pragma unroll
          for (int r = 0; r < 4; r++) pk[r] = f2bf(pout[nt][r]);
          *(u16x4*)(&Pl[w][l15*PLW + ntl*16 + l4*4]) = pk;
        }
        bf16x8 pa = ld8(&Pl[w][l15*PLW + l4*8]);
        __builtin_amdgcn_s_setprio(1);
        #pragma unroll
        for (int n8 = 0; n8 < 8; n8++){
          bf16x8 vf = ld8(&Vl[buf][0] + (n8*16 + l15)*64 + (((kk*4 + l4) ^ (l15&7))<<3));
          ao[n8] = __builtin_amdgcn_mfma_f32_16x16x32_bf16(vf, pa, ao[n8], 0, 0, 0);
        }
        __builtin_amdgcn_s_setprio(0);
      }
    }
    BARRIER();
  }
  asm volatile("s_waitcnt vmcnt(0)" ::: "memory");

  const float inv = 1.0f / li;
  const size_t orow = (size_t)(b*SS + qg)*EE + h*DD;
  #pragma unroll
  for (int n8 = 0; n8 < 8; n8++){
    f32x4 o = ao[n8]*inv;
    *(float4*)(out + orow + n8*16 + l4*4) = __builtin_bit_cast(float4, o);
  }
}

// ---------------- launch ----------------
extern "C" void kernel_launch(void* const* d_in, const int* in_sizes, int n_in,
                              void* d_out, int out_size, void* d_ws, size_t ws_size,
                              hipStream_t stream){
  const float* x    = (const float*)d_in[0];
  const float* Wq   = (const float*)d_in[1];
  const float* Wkvd = (const float*)d_in[2];
  const float* Wku  = (const float*)d_in[3];
  const float* Wvu  = (const float*)d_in[4];
  float* out = (float*)d_out;
  char* ws = (char*)d_ws;

  u16*   xb    = (u16*)  (ws);                 // 33,554,432 B
  u16*   WqT   = (u16*)  (ws +  33554432);     //  8,388,608
  u16*   WkvdT = (u16*)  (ws +  41943040);     //  2,097,152
  u16*   WkuT  = (u16*)  (ws +  44040192);     //  2,097,152  (WvuT adjacent -> 4096xK panel)
  u16*   WvuT  = (u16*)  (ws +  46137344);     //  2,097,152
  float* cosb  = (float*)(ws +  48234496);     //    196,608
  float* sinb  = (float*)(ws +  48431104);     //    196,608
  u16*   qp    = (u16*)  (ws +  48627712);     // 33,554,432
  u16*   ckv   = (u16*)  (ws +  82182144);     //  8,388,608
  u16*   kp    = (u16*)  (ws +  90570752);     // 33,554,432
  u16*   vpT   = (u16*)  (ws + 124125184);     // 33,554,432 (transposed: [bh*128+d][1024])

  prep<<<15552, 256, 0, stream>>>(x, xb, Wq, WqT, Wkvd, WkvdT,
                                  Wku, WkuT, Wvu, WvuT, cosb, sinb);

  // q = x @ Wq  (M=8192, N=2048, K=2048): 256^2 8-phase, 256 blocks, XCD-chunked
  gemm8<1><<<dim3(EE/256, (BB*SS)/256), 512, 0, stream>>>(xb, WqT, qp, qp,
                                                          EE, EE, EE, EE, 0);
  // c_kv = x @ Wkv_down (N=512, K=2048): 128^2, grid 4x64, XCD-chunked
  gemm_bt<<<dim3(512/128, (BB*SS)/128), 256, 0, stream>>>(xb, WkvdT, ckv, BB*SS, 512, EE);
  // fused k/v up-projection (N=4096, K=512): 256 blocks, 2 bn-tiles per block
  // (tile 2 reuses the L2-hot A panel; 1 round instead of 2); V half transposed
  gemm8<2><<<dim3(2048/256, (BB*SS)/256), 512, 0, stream>>>(ckv, WkuT, kp, vpT,
                                                            512, EE, 0, EE, 1);

  rope_apply2<<<dim3((BB*SS*HH)/256, 2), 256, 0, stream>>>(qp, kp, cosb, sinb);

  attn<<<dim3(BB*HH, SS/128), 512, 0, stream>>>(qp, kp, vpT, out);
}